// Round 8
// baseline (28.214 us; speedup 1.0000x reference)
//
#include <hip/hip_runtime.h>

// Problem constants (from reference)
#define V_SZ 100000
#define D_SZ 128
#define B_SZ 4096
#define NEG_SZ 5
#define L_SZ 6

// Deterministic fence-free reduction (proven correct in R5, re-tuned):
//   per block: pair the 2 losses in LDS -> ONE packed add per block.
//   level-1: 64 slots, slot = blockIdx & 63, 32 contributors each:
//            pack = (1<<48) + (bl + 64) * 2^37   (value < 2^43, slot sum
//            < 32*2^43 = 2^48 -> count field at bit 48 never corrupted)
//   level-2: one accumulator, 64 forwards: (1<<56) + slotTotal (< 2^54).
// Finishers detected from the RETURNED old count field -> the data
// dependency flows through the atomic itself, no threadfence needed.
// Integer adds are exact and commutative -> bit-deterministic.
#define FXSCALE 137438953472.0            // 2^37
#define BOFFSET 64.0                      // per-block (2-loss) offset
#define MASK48  ((1ULL << 48) - 1)
#define MASK56  ((1ULL << 56) - 1)

__device__ __forceinline__ float log_sigmoid(float x) {
    // stable: log_sigmoid(x) = min(x,0) - log(1 + exp(-|x|))
    // fast hw transcendentals: error ~1e-6, far under the 8e-2 threshold
    return fminf(x, 0.0f) - __logf(1.0f + __expf(-fabsf(x)));
}

__device__ __forceinline__ float wave_reduce_sum(float v) {
    #pragma unroll
    for (int off = 32; off > 0; off >>= 1) v += __shfl_xor(v, off);
    return v;
}

// TWO batch elements per block (grid = B/2 = 2048, 4 waves of 64) — R6's
// proven body. 14 phrase-pools per block (no duplicate): pool m = wave+4q,
// m in [0,14): b = b0 + m/7, phrase p = m%7 (p=0 -> embed_u, p=1 -> embed_v,
// p=2..6 -> negs 0..4). Waves 0-1 pool 4 phrases, waves 2-3 pool 3.
// Gathers are float4 (16B/lane): lanes 0-31 fetch item 2j, lanes 32-63 item
// 2j+1 -> 3 gathers per phrase. All gathers unconditional (padding indices
// are valid vocab ids); ragged mask applied at accumulation.
// Epilogue: wave 0 finishes b0, wave 1 finishes b1, block pairs the two
// losses in LDS, thread 0 feeds the packed-atomic tree.
__global__ __launch_bounds__(256) void skipgram_fused_kernel(
    const float* __restrict__ u_emb,
    const float* __restrict__ v_emb,
    const int* __restrict__ pos_u_idx,
    const int* __restrict__ pos_u_len,
    const int* __restrict__ pos_v_idx,
    const int* __restrict__ pos_v_len,
    const int* __restrict__ neg_v_idx,
    const int* __restrict__ neg_v_len,
    unsigned long long* __restrict__ slots,   // ws: 64 level-1 + 1 level-2
    float* __restrict__ out)
{
    __shared__ float lds[2][7][D_SZ];   // 7 KiB
    __shared__ float loss_pair[2];

    const int b0   = blockIdx.x * 2;
    const int wave = threadIdx.x >> 6;
    const int lane = threadIdx.x & 63;
    const int half = lane >> 5;          // 0: items 0,2,4 ; 1: items 1,3,5
    const int dof  = (lane & 31) * 4;    // 4 dims per lane within a row

    // ---- up to 4 phrase descriptors (wave-uniform) ----
    const int* idxp[4];
    const float* tab[4];
    int n[4], sb[4], sp[4];
    bool act[4];
    #pragma unroll
    for (int q = 0; q < 4; ++q) {
        const int m = wave + 4 * q;
        act[q] = (m < 14);
        const int mm = act[q] ? m : 0;         // safe dummy descriptor
        const int bb = mm / 7;
        const int pp = mm % 7;
        const int b  = b0 + bb;
        sb[q] = bb; sp[q] = pp;
        if (pp == 0) {
            idxp[q] = pos_u_idx + b * L_SZ; tab[q] = u_emb; n[q] = pos_u_len[b] + 1;
        } else if (pp == 1) {
            idxp[q] = pos_v_idx + b * L_SZ; tab[q] = v_emb; n[q] = pos_v_len[b] + 1;
        } else {
            const int m2 = b * NEG_SZ + (pp - 2);
            idxp[q] = neg_v_idx + m2 * L_SZ; tab[q] = v_emb; n[q] = neg_v_len[m2] + 1;
        }
        n[q] = __builtin_amdgcn_readfirstlane(n[q]);
    }

    // ---- indices (wave-uniform -> SGPR, issue early) ----
    int id[4][L_SZ];
    #pragma unroll
    for (int q = 0; q < 4; ++q)
        #pragma unroll
        for (int l = 0; l < L_SZ; ++l)
            id[q][l] = __builtin_amdgcn_readfirstlane(idxp[q][l]);

    // ---- unconditional float4 row-gathers (2 rows per instruction) ----
    float4 r[4][3];
    #pragma unroll
    for (int q = 0; q < 4; ++q)
        #pragma unroll
        for (int j = 0; j < 3; ++j) {
            const int idx = half ? id[q][2 * j + 1] : id[q][2 * j];
            r[q][j] = *reinterpret_cast<const float4*>(
                &tab[q][(size_t)idx * D_SZ + dof]);
        }

    // ---- masked accumulate, combine halves, scale, store to LDS ----
    #pragma unroll
    for (int q = 0; q < 4; ++q) {
        float4 a = make_float4(0.f, 0.f, 0.f, 0.f);
        #pragma unroll
        for (int j = 0; j < 3; ++j) {
            const bool valid = (2 * j + half) < n[q];
            a.x += valid ? r[q][j].x : 0.f;
            a.y += valid ? r[q][j].y : 0.f;
            a.z += valid ? r[q][j].z : 0.f;
            a.w += valid ? r[q][j].w : 0.f;
        }
        a.x += __shfl_xor(a.x, 32);
        a.y += __shfl_xor(a.y, 32);
        a.z += __shfl_xor(a.z, 32);
        a.w += __shfl_xor(a.w, 32);
        const float inv = 1.0f / (float)n[q];
        a.x *= inv; a.y *= inv; a.z *= inv; a.w *= inv;
        if (act[q] && lane < 32)
            *reinterpret_cast<float4*>(&lds[sb[q]][sp[q]][dof]) = a;
    }
    __syncthreads();

    // ---- wave 0 finishes b0, wave 1 finishes b1 ----
    if (wave < 2) {
        const float2 eu = *reinterpret_cast<const float2*>(&lds[wave][0][2 * lane]);
        float s[6];
        #pragma unroll
        for (int k = 0; k < 6; ++k) {
            const float2 vp = *reinterpret_cast<const float2*>(
                &lds[wave][k + 1][2 * lane]);
            s[k] = eu.x * vp.x + eu.y * vp.y;
        }
        #pragma unroll
        for (int k = 0; k < 6; ++k) s[k] = wave_reduce_sum(s[k]);
        if (lane == 0) {
            float loss = log_sigmoid(s[0]);           // positive pair
            #pragma unroll
            for (int k = 1; k < 6; ++k) loss += log_sigmoid(-s[k]);
            loss_pair[wave] = fmaxf(loss, -31.9f);    // pack-range safety
        }
    }
    __syncthreads();

    // ---- thread 0: one packed add per block into the tree ----
    if (threadIdx.x == 0) {
        const float bl = loss_pair[0] + loss_pair[1];     // in (-64, 0]
        const unsigned long long pack =
            (1ULL << 48) +
            (unsigned long long)llrint(((double)bl + BOFFSET) * FXSCALE);
        const unsigned long long old1 = atomicAdd(&slots[blockIdx.x & 63], pack);
        if ((old1 >> 48) == 31) {                         // 32nd arriver
            const unsigned long long v1 = (old1 + pack) & MASK48;
            const unsigned long long pack2 = (1ULL << 56) + v1;
            const unsigned long long old2 = atomicAdd(&slots[64], pack2);
            if ((old2 >> 56) == 63) {                     // 64th forward
                const unsigned long long tot = (old2 + pack2) & MASK56;
                const double sum_loss =
                    (double)tot / FXSCALE - BOFFSET * (double)(B_SZ / 2);
                out[0] = (float)(-sum_loss / (double)B_SZ);
            }
        }
    }
}

// Fallback (ws unusable): float atomics directly into d_out.
__global__ __launch_bounds__(256) void skipgram_atomic_fallback(
    const float* __restrict__ u_emb,
    const float* __restrict__ v_emb,
    const int* __restrict__ pos_u_idx,
    const int* __restrict__ pos_u_len,
    const int* __restrict__ pos_v_idx,
    const int* __restrict__ pos_v_len,
    const int* __restrict__ neg_v_idx,
    const int* __restrict__ neg_v_len,
    float* __restrict__ out)
{
    const int wave = threadIdx.x >> 6;
    const int lane = threadIdx.x & 63;
    const int b    = blockIdx.x * 4 + wave;
    const int half = lane >> 5;
    const int dof  = (lane & 31) * 4;

    int n[7];
    n[0] = pos_u_len[b] + 1;
    n[1] = pos_v_len[b] + 1;
    #pragma unroll
    for (int k = 0; k < NEG_SZ; ++k) n[2 + k] = neg_v_len[b * NEG_SZ + k] + 1;
    int id[7][L_SZ];
    #pragma unroll
    for (int l = 0; l < L_SZ; ++l) id[0][l] = pos_u_idx[b * L_SZ + l];
    #pragma unroll
    for (int l = 0; l < L_SZ; ++l) id[1][l] = pos_v_idx[b * L_SZ + l];
    #pragma unroll
    for (int k = 0; k < NEG_SZ; ++k)
        #pragma unroll
        for (int l = 0; l < L_SZ; ++l)
            id[2 + k][l] = neg_v_idx[(b * NEG_SZ + k) * L_SZ + l];

    float4 a[7];
    #pragma unroll
    for (int p = 0; p < 7; ++p) {
        const float* t = (p == 0) ? u_emb : v_emb;
        float4 acc = make_float4(0.f, 0.f, 0.f, 0.f);
        #pragma unroll
        for (int j = 0; j < 3; ++j) {
            const int idx = half ? id[p][2 * j + 1] : id[p][2 * j];
            const float4 r = *reinterpret_cast<const float4*>(
                &t[(size_t)idx * D_SZ + dof]);
            const bool valid = (2 * j + half) < n[p];
            acc.x += valid ? r.x : 0.f;
            acc.y += valid ? r.y : 0.f;
            acc.z += valid ? r.z : 0.f;
            acc.w += valid ? r.w : 0.f;
        }
        acc.x += __shfl_xor(acc.x, 32);
        acc.y += __shfl_xor(acc.y, 32);
        acc.z += __shfl_xor(acc.z, 32);
        acc.w += __shfl_xor(acc.w, 32);
        const float inv = 1.0f / (float)n[p];
        acc.x *= inv; acc.y *= inv; acc.z *= inv; acc.w *= inv;
        a[p] = acc;
    }
    float s[6];
    #pragma unroll
    for (int k = 0; k < 6; ++k)
        s[k] = a[0].x * a[k + 1].x + a[0].y * a[k + 1].y +
               a[0].z * a[k + 1].z + a[0].w * a[k + 1].w;
    #pragma unroll
    for (int k = 0; k < 6; ++k)
        #pragma unroll
        for (int off = 16; off > 0; off >>= 1) s[k] += __shfl_xor(s[k], off);
    if (lane == 0) {
        float loss = log_sigmoid(s[0]);
        #pragma unroll
        for (int k = 1; k < 6; ++k) loss += log_sigmoid(-s[k]);
        atomicAdd(out, -loss / (float)B_SZ);
    }
}

extern "C" void kernel_launch(void* const* d_in, const int* in_sizes, int n_in,
                              void* d_out, int out_size, void* d_ws, size_t ws_size,
                              hipStream_t stream) {
    const float* u_emb     = (const float*)d_in[0];
    const float* v_emb     = (const float*)d_in[1];
    const int*   pos_u_idx = (const int*)d_in[2];
    const int*   pos_u_len = (const int*)d_in[3];
    const int*   pos_v_idx = (const int*)d_in[4];
    const int*   pos_v_len = (const int*)d_in[5];
    const int*   neg_v_idx = (const int*)d_in[6];
    const int*   neg_v_len = (const int*)d_in[7];
    float* out = (float*)d_out;

    const size_t need = 65 * sizeof(unsigned long long);
    if (ws_size >= need) {
        unsigned long long* slots = (unsigned long long*)d_ws;
        hipMemsetAsync(d_ws, 0, need, stream);        // 520 B, cheap leading dispatch
        skipgram_fused_kernel<<<B_SZ / 2, 256, 0, stream>>>(
            u_emb, v_emb, pos_u_idx, pos_u_len, pos_v_idx, pos_v_len,
            neg_v_idx, neg_v_len, slots, out);
    } else {
        hipMemsetAsync(d_out, 0, sizeof(float), stream);
        skipgram_atomic_fallback<<<B_SZ / 4, 256, 0, stream>>>(
            u_emb, v_emb, pos_u_idx, pos_u_len, pos_v_idx, pos_v_len,
            neg_v_idx, neg_v_len, out);
    }
}

// Round 9
// 22.374 us; speedup vs baseline: 1.2610x; 1.2610x over previous
//
#include <hip/hip_runtime.h>

// Problem constants (from reference)
#define V_SZ 100000
#define D_SZ 128
#define B_SZ 4096
#define NEG_SZ 5
#define L_SZ 6

__device__ __forceinline__ float log_sigmoid(float x) {
    // stable: log_sigmoid(x) = min(x,0) - log(1 + exp(-|x|))
    // fast hw transcendentals: error ~1e-6, far under the 8e-2 threshold
    return fminf(x, 0.0f) - __logf(1.0f + __expf(-fabsf(x)));
}

__device__ __forceinline__ float wave_reduce_sum(float v) {
    #pragma unroll
    for (int off = 32; off > 0; off >>= 1) v += __shfl_xor(v, off);
    return v;
}

// TWO batch elements per block (grid = B/2 = 2048, 4 waves of 64).
// Per b, phrase-slots 0..7: p=0 -> embed_u, p=1 -> embed_v, p=2..6 -> negs
// 0..4, p=7 -> duplicate of p=3 (benign, same data, distinct LDS slot).
// Wave w pools 4 phrases: (b0, w), (b0, w+4), (b1, w), (b1, w+4)
//   -> 12 float4 row-gathers in flight per wave (2 rows per instruction:
//      lanes 0-31 fetch item 2j, lanes 32-63 item 2j+1).
// All gathers unconditional (padding indices are valid vocab ids); ragged
// mask applied at accumulation. Epilogue: wave 0 finishes b0, wave 1
// finishes b1 (6 dots from LDS + log-sigmoids), plain store to per_b[].
//
// Measured best structure (R6 = 22.48 us). Atomic-tail variants (R4/R5/R8)
// all regressed: same-address L2 RMWs serialize at ~90 ns; both structures
// cost 2 dispatches anyway, so the dedicated reduce kernel wins.
__global__ __launch_bounds__(256) void skipgram_loss_kernel(
    const float* __restrict__ u_emb,
    const float* __restrict__ v_emb,
    const int* __restrict__ pos_u_idx,
    const int* __restrict__ pos_u_len,
    const int* __restrict__ pos_v_idx,
    const int* __restrict__ pos_v_len,
    const int* __restrict__ neg_v_idx,
    const int* __restrict__ neg_v_len,
    float* __restrict__ per_b)
{
    __shared__ float lds[2][8][D_SZ];   // 8 KiB

    const int b0   = blockIdx.x * 2;
    const int wave = threadIdx.x >> 6;
    const int lane = threadIdx.x & 63;
    const int half = lane >> 5;          // 0: items 0,2,4 ; 1: items 1,3,5
    const int dof  = (lane & 31) * 4;    // 4 dims per lane within a row

    // ---- 4 phrase descriptors (wave-uniform) ----
    const int* idxp[4];
    const float* tab[4];
    int n[4], sb[4], sp[4];
    #pragma unroll
    for (int q = 0; q < 4; ++q) {
        const int bb = q >> 1;                 // 0,0,1,1
        const int pp = wave + 4 * (q & 1);     // w, w+4
        const int b  = b0 + bb;
        const int eff = (pp == 7) ? 3 : pp;    // slot 7 duplicates neg #1
        sb[q] = bb; sp[q] = pp;
        if (eff == 0) {
            idxp[q] = pos_u_idx + b * L_SZ; tab[q] = u_emb; n[q] = pos_u_len[b] + 1;
        } else if (eff == 1) {
            idxp[q] = pos_v_idx + b * L_SZ; tab[q] = v_emb; n[q] = pos_v_len[b] + 1;
        } else {
            const int m = b * NEG_SZ + (eff - 2);
            idxp[q] = neg_v_idx + m * L_SZ; tab[q] = v_emb; n[q] = neg_v_len[m] + 1;
        }
        n[q] = __builtin_amdgcn_readfirstlane(n[q]);
    }

    // ---- all 24 indices (wave-uniform -> SGPR, issue early) ----
    int id[4][L_SZ];
    #pragma unroll
    for (int q = 0; q < 4; ++q)
        #pragma unroll
        for (int l = 0; l < L_SZ; ++l)
            id[q][l] = __builtin_amdgcn_readfirstlane(idxp[q][l]);

    // ---- 12 unconditional float4 row-gathers (2 rows per instruction) ----
    float4 r[4][3];
    #pragma unroll
    for (int q = 0; q < 4; ++q)
        #pragma unroll
        for (int j = 0; j < 3; ++j) {
            const int idx = half ? id[q][2 * j + 1] : id[q][2 * j];
            r[q][j] = *reinterpret_cast<const float4*>(
                &tab[q][(size_t)idx * D_SZ + dof]);
        }

    // ---- masked accumulate, combine halves, scale, store to LDS ----
    #pragma unroll
    for (int q = 0; q < 4; ++q) {
        float4 a = make_float4(0.f, 0.f, 0.f, 0.f);
        #pragma unroll
        for (int j = 0; j < 3; ++j) {
            const bool valid = (2 * j + half) < n[q];
            a.x += valid ? r[q][j].x : 0.f;
            a.y += valid ? r[q][j].y : 0.f;
            a.z += valid ? r[q][j].z : 0.f;
            a.w += valid ? r[q][j].w : 0.f;
        }
        a.x += __shfl_xor(a.x, 32);
        a.y += __shfl_xor(a.y, 32);
        a.z += __shfl_xor(a.z, 32);
        a.w += __shfl_xor(a.w, 32);
        const float inv = 1.0f / (float)n[q];
        a.x *= inv; a.y *= inv; a.z *= inv; a.w *= inv;
        if (lane < 32)
            *reinterpret_cast<float4*>(&lds[sb[q]][sp[q]][dof]) = a;
    }
    __syncthreads();

    // ---- wave 0 finishes b0, wave 1 finishes b1 ----
    if (wave < 2) {
        const float2 eu = *reinterpret_cast<const float2*>(&lds[wave][0][2 * lane]);
        float s[6];
        #pragma unroll
        for (int k = 0; k < 6; ++k) {
            const float2 vp = *reinterpret_cast<const float2*>(
                &lds[wave][k + 1][2 * lane]);
            s[k] = eu.x * vp.x + eu.y * vp.y;
        }
        #pragma unroll
        for (int k = 0; k < 6; ++k) s[k] = wave_reduce_sum(s[k]);
        if (lane == 0) {
            float loss = log_sigmoid(s[0]);           // positive pair
            #pragma unroll
            for (int k = 1; k < 6; ++k) loss += log_sigmoid(-s[k]);
            per_b[b0 + wave] = loss;
        }
    }
}

__global__ __launch_bounds__(256) void skipgram_reduce_kernel(
    const float* __restrict__ per_b, float* __restrict__ out)
{
    __shared__ float s[4];
    // 4096 floats = 1024 float4 = 4 float4 per thread, fully unrolled
    float acc = 0.0f;
    #pragma unroll
    for (int i = 0; i < 4; ++i) {
        const float4 v = reinterpret_cast<const float4*>(per_b)[
            i * 256 + threadIdx.x];
        acc += (v.x + v.y) + (v.z + v.w);
    }
    acc = wave_reduce_sum(acc);
    const int wave = threadIdx.x >> 6;
    const int lane = threadIdx.x & 63;
    if (lane == 0) s[wave] = acc;
    __syncthreads();
    if (threadIdx.x == 0) {
        out[0] = -(s[0] + s[1] + s[2] + s[3]) / (float)B_SZ;
    }
}

extern "C" void kernel_launch(void* const* d_in, const int* in_sizes, int n_in,
                              void* d_out, int out_size, void* d_ws, size_t ws_size,
                              hipStream_t stream) {
    const float* u_emb     = (const float*)d_in[0];
    const float* v_emb     = (const float*)d_in[1];
    const int*   pos_u_idx = (const int*)d_in[2];
    const int*   pos_u_len = (const int*)d_in[3];
    const int*   pos_v_idx = (const int*)d_in[4];
    const int*   pos_v_len = (const int*)d_in[5];
    const int*   neg_v_idx = (const int*)d_in[6];
    const int*   neg_v_len = (const int*)d_in[7];
    float* out = (float*)d_out;

    float* per_b = (float*)d_ws;   // 16 KiB; ws is far larger
    skipgram_loss_kernel<<<B_SZ / 2, 256, 0, stream>>>(
        u_emb, v_emb, pos_u_idx, pos_u_len, pos_v_idx, pos_v_len,
        neg_v_idx, neg_v_len, per_b);
    skipgram_reduce_kernel<<<1, 256, 0, stream>>>(per_b, out);
}